// Round 6
// baseline (469.779 us; speedup 1.0000x reference)
//
#include <hip/hip_runtime.h>
#include <hip/hip_bf16.h>
#include <cstdint>

typedef unsigned short u16;
typedef __bf16 bf16x8 __attribute__((ext_vector_type(8)));
typedef float floatx4 __attribute__((ext_vector_type(4)));

#define AS1 __attribute__((address_space(1)))
#define AS3 __attribute__((address_space(3)))

// round-to-nearest-even f32 -> bf16 bits
static __device__ __forceinline__ u16 f2bf(float f) {
    union { float f; unsigned int u; } v; v.f = f;
    unsigned int u = v.u;
    return (u16)((u + 0x7FFFu + ((u >> 16) & 1u)) >> 16);
}

// ---------------------------------------------------------------------------
// Fused prep kernel: blockIdx-partitioned into
//   [0, 4096)      : transpose+cvt w1 (1024x4096 -> W1t[4096][1024])
//   [4096, 8192)   : transpose+cvt w2 (4096x1024 -> W2t[1024][4096])
//   [8192, 16384)  : LayerNorm row (act row -> X row, bf16)
// ---------------------------------------------------------------------------
__device__ __forceinline__ void transpose_body(
    const float* __restrict__ in, u16* __restrict__ out,
    int R, int Ccols, int bx, int by, int tid, float (*tile)[33])
{
    const int tx = tid & 31;
    const int ty = tid >> 5;    // 0..7
    const int c0 = bx * 32;
    const int r0 = by * 32;
#pragma unroll
    for (int i = 0; i < 32; i += 8)
        tile[ty + i][tx] = in[(size_t)(r0 + ty + i) * Ccols + (c0 + tx)];
    __syncthreads();
#pragma unroll
    for (int i = 0; i < 32; i += 8)
        out[(size_t)(c0 + ty + i) * R + (r0 + tx)] = f2bf(tile[tx][ty + i]);
}

__global__ __launch_bounds__(256)
void prep(const float* __restrict__ w1, const float* __restrict__ w2,
          const float* __restrict__ act, const float* __restrict__ ln_scale,
          const float* __restrict__ ln_bias,
          u16* __restrict__ W1t, u16* __restrict__ W2t, u16* __restrict__ X)
{
    __shared__ float smem[32][33];   // transpose tile; LN uses first 8 floats
    const int id  = blockIdx.x;
    const int tid = threadIdx.x;

    if (id < 4096) {
        transpose_body(w1, W1t, 1024, 4096, id & 127, id >> 7, tid, smem);
        return;
    }
    if (id < 8192) {
        const int t = id - 4096;
        transpose_body(w2, W2t, 4096, 1024, t & 31, t >> 5, tid, smem);
        return;
    }
    // LayerNorm, one block per row
    const int row = id - 8192;
    const float4 v = ((const float4*)(act + (size_t)row * 1024))[tid];
    float s  = v.x + v.y + v.z + v.w;
    float ss = v.x * v.x + v.y * v.y + v.z * v.z + v.w * v.w;
#pragma unroll
    for (int off = 32; off > 0; off >>= 1) {
        s  += __shfl_xor(s, off, 64);
        ss += __shfl_xor(ss, off, 64);
    }
    float* red = &smem[0][0];
    const int wave = tid >> 6, lane = tid & 63;
    if (lane == 0) { red[wave] = s; red[4 + wave] = ss; }
    __syncthreads();
    s  = red[0] + red[1] + red[2] + red[3];
    ss = red[4] + red[5] + red[6] + red[7];
    const float mu  = s * (1.0f / 1024.0f);
    const float var = ss * (1.0f / 1024.0f) - mu * mu;
    const float rs  = rsqrtf(var + 1e-5f);
    const float4 sc = ((const float4*)ln_scale)[tid];
    const float4 bi = ((const float4*)ln_bias)[tid];
    ushort4 o;
    o.x = f2bf((v.x - mu) * rs * sc.x + bi.x);
    o.y = f2bf((v.y - mu) * rs * sc.y + bi.y);
    o.z = f2bf((v.z - mu) * rs * sc.z + bi.z);
    o.w = f2bf((v.w - mu) * rs * sc.w + bi.w);
    ((ushort4*)(X + (size_t)row * 1024))[tid] = o;
}

// ---------------------------------------------------------------------------
// bf16 GEMM: C[M][N] = A[M][K] * Bt[N][K]^T + bias (+ReLU)
// 128x128 block tile, BK=64, 4 waves (2x2), each wave 4x4 MFMA 16x16x32
// tiles. global_load_lds width-16 staging + XOR bank swizzle (R2: conflicts
// 8.39M -> 0). Operand-swapped MFMA -> contiguous float4/ushort4 epilogue.
//
// Block order: plain bm-fastest 1D (R3-proven). R5's group-8 swizzle REGRESSED
// (FETCH 57 -> 139.6 MB): XCD round-robin (xcd = id%8) made bm == xcd, so
// every XCD streamed the whole B matrix through its private L2. bm-fastest
// keeps bm%8 pinned per XCD -> A-stripe (2 MB) L2-resident.
//
// NO forced min-occupancy (R4: launch_bounds(256,5) -> acc spill, 2x slower).
//
// SPLITK>1 (GEMM2): block s covers k in [s*K/SPLITK, (s+1)*K/SPLITK);
// epilogue atomicAdd f32 (device-scope, m20) into zeroed output; bias added
// by s==0 only. Raises 512-block GEMM2 to 1024 blocks = 4/CU residency.
// ---------------------------------------------------------------------------
template <int BK, int SPLITK, bool BF16_OUT, bool RELU>
__global__ __launch_bounds__(256)
void gemm_bt(const u16* __restrict__ A,      // [M][K] bf16 bits
             const u16* __restrict__ Bt,     // [N][K] bf16 bits
             const float* __restrict__ bias, // [N]
             void* __restrict__ Cout,
             int M, int N, int K)
{
    constexpr int SLOTS  = BK / 8;      // 16B slots per LDS row
    constexpr int RPI    = 64 / SLOTS;  // rows covered per 1KB wave issue
    constexpr int IPW    = SLOTS / 2;   // issues per wave per matrix
    constexpr int HALVES = BK / 32;     // k-halves per LDS tile

    __shared__ __align__(16) u16 Alds[128 * BK];
    __shared__ __align__(16) u16 Blds[128 * BK];

    const int tid  = threadIdx.x;
    const int wave = tid >> 6;
    const int lane = tid & 63;
    const int wm   = wave & 1;
    const int wn   = wave >> 1;
    const int quad = lane >> 4;
    const int l16  = lane & 15;

    // plain bm-fastest decomposition (+ split-K slice)
    const int nbm = M >> 7;
    const int nbn = N >> 7;
    int id = blockIdx.x;
    const int s   = (SPLITK > 1) ? id / (nbm * nbn) : 0;
    if (SPLITK > 1) id -= s * nbm * nbn;
    const int bm  = id % nbm;
    const int bn  = id / nbm;
    const int Ks   = K / SPLITK;
    const int kbeg = s * Ks;
    const int kend = kbeg + Ks;

    const u16* Ag = A  + (size_t)bm * 128 * K;
    const u16* Bg = Bt + (size_t)bn * 128 * K;

    // staging: lane -> (row srow, stored slot s_st); fetch global slot
    // s_g = s_st ^ key(srow) so read-time slot q^key(row) yields global q.
    const int srow = lane / SLOTS;
    const int s_st = lane & (SLOTS - 1);
    const int s_g  = (SLOTS == 4) ? (s_st ^ ((srow >> 1) & 3))
                                  : (s_st ^ (srow & 7));
    const int scol = s_g * 8;

    // read-side swizzle key (per-lane constant)
    const int rkey = (SLOTS == 4) ? ((l16 >> 1) & 3) : (l16 & 7);

    floatx4 acc[4][4];
#pragma unroll
    for (int i = 0; i < 4; ++i)
#pragma unroll
        for (int j = 0; j < 4; ++j)
            acc[i][j] = (floatx4){0.f, 0.f, 0.f, 0.f};

    for (int k0 = kbeg; k0 < kend; k0 += BK) {
        __syncthreads();   // previous iteration's LDS reads done
#pragma unroll
        for (int r = 0; r < IPW; ++r) {
            const int chunk = wave * IPW + r;
            const int row = chunk * RPI + srow;
            __builtin_amdgcn_global_load_lds(
                (AS1 void*)(Ag + (size_t)row * K + k0 + scol),
                (AS3 void*)(&Alds[chunk * 512]), 16, 0, 0);
            __builtin_amdgcn_global_load_lds(
                (AS1 void*)(Bg + (size_t)row * K + k0 + scol),
                (AS3 void*)(&Blds[chunk * 512]), 16, 0, 0);
        }
        __syncthreads();   // staging drained

#pragma unroll
        for (int h = 0; h < HALVES; ++h) {
            const int slot = ((quad + 4 * h) ^ rkey) * 8;
            bf16x8 bfr[4];
#pragma unroll
            for (int ni = 0; ni < 4; ++ni) {
                const int brow = wn * 64 + ni * 16 + l16;
                bfr[ni] = *(const bf16x8*)(&Blds[brow * BK + slot]);
            }
#pragma unroll
            for (int mi = 0; mi < 4; ++mi) {
                const int arow = wm * 64 + mi * 16 + l16;
                const bf16x8 a = *(const bf16x8*)(&Alds[arow * BK + slot]);
                // swapped operands: D[i=n (quad*4+reg)][j=m (l16)]
#pragma unroll
                for (int ni = 0; ni < 4; ++ni)
                    acc[mi][ni] = __builtin_amdgcn_mfma_f32_16x16x32_bf16(
                        bfr[ni], a, acc[mi][ni], 0, 0, 0);
            }
        }
    }

    // epilogue: lane (l16, quad) of acc[mi][ni] holds
    //   C[m = mbase+mi*16+l16][n = nbase+ni*16+quad*4 + r], r=0..3 contiguous
    const int mbase = bm * 128 + wm * 64;
    const int nbase = bn * 128 + wn * 64;
    const bool add_bias = (SPLITK == 1) || (s == 0);
#pragma unroll
    for (int mi = 0; mi < 4; ++mi) {
        const int m = mbase + mi * 16 + l16;
#pragma unroll
        for (int ni = 0; ni < 4; ++ni) {
            const int n0 = nbase + ni * 16 + quad * 4;
            const float4 bv = *(const float4*)&bias[n0];
            float v0 = acc[mi][ni][0], v1 = acc[mi][ni][1];
            float v2 = acc[mi][ni][2], v3 = acc[mi][ni][3];
            if (add_bias) { v0 += bv.x; v1 += bv.y; v2 += bv.z; v3 += bv.w; }
            if (RELU) {
                v0 = fmaxf(v0, 0.f); v1 = fmaxf(v1, 0.f);
                v2 = fmaxf(v2, 0.f); v3 = fmaxf(v3, 0.f);
            }
            if (SPLITK > 1) {
                float* p = &((float*)Cout)[(size_t)m * N + n0];
                atomicAdd(p + 0, v0); atomicAdd(p + 1, v1);
                atomicAdd(p + 2, v2); atomicAdd(p + 3, v3);
            } else if (BF16_OUT) {
                ushort4 o = { f2bf(v0), f2bf(v1), f2bf(v2), f2bf(v3) };
                *(ushort4*)&((u16*)Cout)[(size_t)m * N + n0] = o;
            } else {
                float4 o = { v0, v1, v2, v3 };
                *(float4*)&((float*)Cout)[(size_t)m * N + n0] = o;
            }
        }
    }
}

// ---------------------------------------------------------------------------
// inputs: 0 act(4,2048,1024) f32, 1 mask(unused), 2 ln_scale(1024),
//         3 ln_bias(1024), 4 w1(1024,4096), 5 b1(4096), 6 w2(4096,1024),
//         7 b2(1024). out: (4,2048,1024) f32.
// ws layout (bf16 bits): X[8192*1024] | W1t[4096*1024] | W2t[1024*4096] |
//                        H[8192*4096]  -> 100,663,296 bytes total
// ---------------------------------------------------------------------------
extern "C" void kernel_launch(void* const* d_in, const int* in_sizes, int n_in,
                              void* d_out, int out_size, void* d_ws, size_t ws_size,
                              hipStream_t stream)
{
    const float* act      = (const float*)d_in[0];
    const float* ln_scale = (const float*)d_in[2];
    const float* ln_bias  = (const float*)d_in[3];
    const float* w1       = (const float*)d_in[4];
    const float* b1       = (const float*)d_in[5];
    const float* w2       = (const float*)d_in[6];
    const float* b2       = (const float*)d_in[7];
    float* out = (float*)d_out;

    const int M = 8192, C = 1024, CI = 4096;

    u16* X   = (u16*)d_ws;                 // [M][C]
    u16* W1t = X   + (size_t)M * C;        // [CI][C]
    u16* W2t = W1t + (size_t)CI * C;       // [C][CI]
    u16* H   = W2t + (size_t)C * CI;       // [M][CI]

    // zero the output for split-K atomic accumulation (graph-capturable)
    hipMemsetAsync(out, 0, (size_t)M * C * sizeof(float), stream);
    // fused prep: w1/w2 transpose+cvt + layernorm, one launch
    prep<<<16384, 256, 0, stream>>>(w1, w2, act, ln_scale, ln_bias, W1t, W2t, X);
    // H = relu(X @ W1 + b1), bf16
    gemm_bt<64, 1, true, true><<<(M / 128) * (CI / 128), 256, 0, stream>>>(
        X, W1t, b1, (void*)H, M, CI, C);
    // out = H @ W2 + b2, fp32, split-K=2 (1024 blocks = 4/CU residency)
    gemm_bt<64, 2, false, false><<<(M / 128) * (C / 128) * 2, 256, 0, stream>>>(
        H, W2t, b2, (void*)out, M, C, CI);
}

// Round 7
// 266.923 us; speedup vs baseline: 1.7600x; 1.7600x over previous
//
#include <hip/hip_runtime.h>
#include <hip/hip_bf16.h>
#include <cstdint>

typedef unsigned short u16;
typedef __bf16 bf16x8 __attribute__((ext_vector_type(8)));
typedef float floatx4 __attribute__((ext_vector_type(4)));

#define AS1 __attribute__((address_space(1)))
#define AS3 __attribute__((address_space(3)))

// round-to-nearest-even f32 -> bf16 bits
static __device__ __forceinline__ u16 f2bf(float f) {
    union { float f; unsigned int u; } v; v.f = f;
    unsigned int u = v.u;
    return (u16)((u + 0x7FFFu + ((u >> 16) & 1u)) >> 16);
}

// ---------------------------------------------------------------------------
// Fused prep kernel: blockIdx-partitioned into
//   [0, 4096)      : transpose+cvt w1 (1024x4096 -> W1t[4096][1024])
//   [4096, 8192)   : transpose+cvt w2 (4096x1024 -> W2t[1024][4096])
//   [8192, 16384)  : LayerNorm row (act row -> X row, bf16)
// ---------------------------------------------------------------------------
__device__ __forceinline__ void transpose_body(
    const float* __restrict__ in, u16* __restrict__ out,
    int R, int Ccols, int bx, int by, int tid, float (*tile)[33])
{
    const int tx = tid & 31;
    const int ty = tid >> 5;    // 0..7
    const int c0 = bx * 32;
    const int r0 = by * 32;
#pragma unroll
    for (int i = 0; i < 32; i += 8)
        tile[ty + i][tx] = in[(size_t)(r0 + ty + i) * Ccols + (c0 + tx)];
    __syncthreads();
#pragma unroll
    for (int i = 0; i < 32; i += 8)
        out[(size_t)(c0 + ty + i) * R + (r0 + tx)] = f2bf(tile[tx][ty + i]);
}

__global__ __launch_bounds__(256)
void prep(const float* __restrict__ w1, const float* __restrict__ w2,
          const float* __restrict__ act, const float* __restrict__ ln_scale,
          const float* __restrict__ ln_bias,
          u16* __restrict__ W1t, u16* __restrict__ W2t, u16* __restrict__ X)
{
    __shared__ float smem[32][33];   // transpose tile; LN uses first 8 floats
    const int id  = blockIdx.x;
    const int tid = threadIdx.x;

    if (id < 4096) {
        transpose_body(w1, W1t, 1024, 4096, id & 127, id >> 7, tid, smem);
        return;
    }
    if (id < 8192) {
        const int t = id - 4096;
        transpose_body(w2, W2t, 4096, 1024, t & 31, t >> 5, tid, smem);
        return;
    }
    // LayerNorm, one block per row
    const int row = id - 8192;
    const float4 v = ((const float4*)(act + (size_t)row * 1024))[tid];
    float s  = v.x + v.y + v.z + v.w;
    float ss = v.x * v.x + v.y * v.y + v.z * v.z + v.w * v.w;
#pragma unroll
    for (int off = 32; off > 0; off >>= 1) {
        s  += __shfl_xor(s, off, 64);
        ss += __shfl_xor(ss, off, 64);
    }
    float* red = &smem[0][0];
    const int wave = tid >> 6, lane = tid & 63;
    if (lane == 0) { red[wave] = s; red[4 + wave] = ss; }
    __syncthreads();
    s  = red[0] + red[1] + red[2] + red[3];
    ss = red[4] + red[5] + red[6] + red[7];
    const float mu  = s * (1.0f / 1024.0f);
    const float var = ss * (1.0f / 1024.0f) - mu * mu;
    const float rs  = rsqrtf(var + 1e-5f);
    const float4 sc = ((const float4*)ln_scale)[tid];
    const float4 bi = ((const float4*)ln_bias)[tid];
    ushort4 o;
    o.x = f2bf((v.x - mu) * rs * sc.x + bi.x);
    o.y = f2bf((v.y - mu) * rs * sc.y + bi.y);
    o.z = f2bf((v.z - mu) * rs * sc.z + bi.z);
    o.w = f2bf((v.w - mu) * rs * sc.w + bi.w);
    ((ushort4*)(X + (size_t)row * 1024))[tid] = o;
}

// ---------------------------------------------------------------------------
// bf16 GEMM: C[M][N] = A[M][K] * Bt[N][K]^T + bias (+ReLU)
// 128x128 block tile, templated BK (64 or 128), 4 waves (2x2), each wave
// 4x4 MFMA 16x16x32 tiles. global_load_lds width-16 staging + XOR bank
// swizzle (R2: conflicts 8.39M -> 0). Operand-swapped MFMA -> contiguous
// float4/ushort4 epilogue.
//
// Block order: plain bm-fastest 1D. (R5: group-8 swizzle collided with XCD
// round-robin -> FETCH 2.4x. R6: atomic split-K -> WRITE 4x, 2.7x slower.
// Both reverted.)
// NO forced min-occupancy (R4: launch_bounds(256,5) -> acc spill).
//
// BK=128 is for grid-limited dispatches only (<=2 blocks/CU by grid): 64KB
// LDS costs no residency there and halves barrier drains (R2's -30% lever).
// ---------------------------------------------------------------------------
template <int BK, bool BF16_OUT, bool RELU>
__global__ __launch_bounds__(256)
void gemm_bt(const u16* __restrict__ A,      // [M][K] bf16 bits
             const u16* __restrict__ Bt,     // [N][K] bf16 bits
             const float* __restrict__ bias, // [N]
             void* __restrict__ Cout,
             int M, int N, int K)
{
    constexpr int SLOTS  = BK / 8;      // 16B slots per LDS row (4/8/16)
    constexpr int RPI    = 64 / SLOTS;  // rows covered per 1KB wave issue
    constexpr int IPW    = SLOTS / 2;   // issues per wave per matrix
    constexpr int HALVES = BK / 32;     // k-halves per LDS tile

    __shared__ __align__(16) u16 Alds[128 * BK];
    __shared__ __align__(16) u16 Blds[128 * BK];

    const int tid  = threadIdx.x;
    const int wave = tid >> 6;
    const int lane = tid & 63;
    const int wm   = wave & 1;
    const int wn   = wave >> 1;
    const int quad = lane >> 4;
    const int l16  = lane & 15;

    // plain bm-fastest decomposition
    const int nbm = M >> 7;
    const int id  = blockIdx.x;
    const int bm  = id % nbm;
    const int bn  = id / nbm;

    const u16* Ag = A  + (size_t)bm * 128 * K;
    const u16* Bg = Bt + (size_t)bn * 128 * K;

    // staging: lane -> (row-within-issue srow, stored slot s_st); fetch
    // global slot s_g = s_st ^ key(row) so read slot q^key(row) = global q.
    const int srow = lane / SLOTS;
    const int s_st = lane & (SLOTS - 1);

    // read-side swizzle key (per-lane constant; frag rows = base16 + l16)
    const int rkey = (SLOTS == 4) ? ((l16 >> 1) & 3) : (l16 & (SLOTS - 1));

    floatx4 acc[4][4];
#pragma unroll
    for (int i = 0; i < 4; ++i)
#pragma unroll
        for (int j = 0; j < 4; ++j)
            acc[i][j] = (floatx4){0.f, 0.f, 0.f, 0.f};

    for (int k0 = 0; k0 < K; k0 += BK) {
        __syncthreads();   // previous iteration's LDS reads done
#pragma unroll
        for (int r = 0; r < IPW; ++r) {
            const int chunk = wave * IPW + r;
            const int row = chunk * RPI + srow;
            const int key = (SLOTS == 4) ? ((row >> 1) & 3)
                                         : (row & (SLOTS - 1));
            const int scol = (s_st ^ key) * 8;
            __builtin_amdgcn_global_load_lds(
                (AS1 void*)(Ag + (size_t)row * K + k0 + scol),
                (AS3 void*)(&Alds[chunk * 512]), 16, 0, 0);
            __builtin_amdgcn_global_load_lds(
                (AS1 void*)(Bg + (size_t)row * K + k0 + scol),
                (AS3 void*)(&Blds[chunk * 512]), 16, 0, 0);
        }
        __syncthreads();   // staging drained

#pragma unroll
        for (int h = 0; h < HALVES; ++h) {
            const int slot = ((quad + 4 * h) ^ rkey) * 8;
            bf16x8 bfr[4];
#pragma unroll
            for (int ni = 0; ni < 4; ++ni) {
                const int brow = wn * 64 + ni * 16 + l16;
                bfr[ni] = *(const bf16x8*)(&Blds[brow * BK + slot]);
            }
#pragma unroll
            for (int mi = 0; mi < 4; ++mi) {
                const int arow = wm * 64 + mi * 16 + l16;
                const bf16x8 a = *(const bf16x8*)(&Alds[arow * BK + slot]);
                // swapped operands: D[i=n (quad*4+reg)][j=m (l16)]
#pragma unroll
                for (int ni = 0; ni < 4; ++ni)
                    acc[mi][ni] = __builtin_amdgcn_mfma_f32_16x16x32_bf16(
                        bfr[ni], a, acc[mi][ni], 0, 0, 0);
            }
        }
    }

    // epilogue: lane (l16, quad) of acc[mi][ni] holds
    //   C[m = mbase+mi*16+l16][n = nbase+ni*16+quad*4 + r], r=0..3 contiguous
    const int mbase = bm * 128 + wm * 64;
    const int nbase = bn * 128 + wn * 64;
#pragma unroll
    for (int mi = 0; mi < 4; ++mi) {
        const int m = mbase + mi * 16 + l16;
#pragma unroll
        for (int ni = 0; ni < 4; ++ni) {
            const int n0 = nbase + ni * 16 + quad * 4;
            const float4 bv = *(const float4*)&bias[n0];
            float v0 = acc[mi][ni][0] + bv.x;
            float v1 = acc[mi][ni][1] + bv.y;
            float v2 = acc[mi][ni][2] + bv.z;
            float v3 = acc[mi][ni][3] + bv.w;
            if (RELU) {
                v0 = fmaxf(v0, 0.f); v1 = fmaxf(v1, 0.f);
                v2 = fmaxf(v2, 0.f); v3 = fmaxf(v3, 0.f);
            }
            if (BF16_OUT) {
                ushort4 o = { f2bf(v0), f2bf(v1), f2bf(v2), f2bf(v3) };
                *(ushort4*)&((u16*)Cout)[(size_t)m * N + n0] = o;
            } else {
                float4 o = { v0, v1, v2, v3 };
                *(float4*)&((float*)Cout)[(size_t)m * N + n0] = o;
            }
        }
    }
}

// ---------------------------------------------------------------------------
// inputs: 0 act(4,2048,1024) f32, 1 mask(unused), 2 ln_scale(1024),
//         3 ln_bias(1024), 4 w1(1024,4096), 5 b1(4096), 6 w2(4096,1024),
//         7 b2(1024). out: (4,2048,1024) f32.
// ws layout (bf16 bits): X[8192*1024] | W1t[4096*1024] | W2t[1024*4096] |
//                        H[8192*4096]  -> 100,663,296 bytes total
// ---------------------------------------------------------------------------
extern "C" void kernel_launch(void* const* d_in, const int* in_sizes, int n_in,
                              void* d_out, int out_size, void* d_ws, size_t ws_size,
                              hipStream_t stream)
{
    const float* act      = (const float*)d_in[0];
    const float* ln_scale = (const float*)d_in[2];
    const float* ln_bias  = (const float*)d_in[3];
    const float* w1       = (const float*)d_in[4];
    const float* b1       = (const float*)d_in[5];
    const float* w2       = (const float*)d_in[6];
    const float* b2       = (const float*)d_in[7];
    float* out = (float*)d_out;

    const int M = 8192, C = 1024, CI = 4096;

    u16* X   = (u16*)d_ws;                 // [M][C]
    u16* W1t = X   + (size_t)M * C;        // [CI][C]
    u16* W2t = W1t + (size_t)CI * C;       // [C][CI]
    u16* H   = W2t + (size_t)C * CI;       // [M][CI]

    // fused prep: w1/w2 transpose+cvt + layernorm, one launch
    prep<<<16384, 256, 0, stream>>>(w1, w2, act, ln_scale, ln_bias, W1t, W2t, X);
    // H = relu(X @ W1 + b1), bf16.  2048 blocks -> BK=64 (BK=128's 64KB LDS
    // would cut residency 3->2 here, m132's regression regime).
    gemm_bt<64, true, true><<<(M / 128) * (CI / 128), 256, 0, stream>>>(
        X, W1t, b1, (void*)H, M, CI, C);
    // out = H @ W2 + b2, fp32.  512 blocks = 2/CU by grid -> BK=128 is free
    // occupancy-wise and halves barrier drains (32 K-iters).
    gemm_bt<128, false, false><<<(M / 128) * (C / 128), 256, 0, stream>>>(
        H, W2t, b2, (void*)out, M, C, CI);
}